// Round 2
// baseline (139.212 us; speedup 1.0000x reference)
//
#include <hip/hip_runtime.h>

// out[e] = dot(h[src[e]], h[dst[e]]), D=128, h f32.
// Pass 1: per-row int8 quantization (q = rint(x*127/rowmax), scale = rowmax/127).
// Pass 2: unsorted gather, 8 edges per 8-lane subgroup.
//         Rounds 5/6 showed the gather is LATENCY-bound (~48us vs ~16us byte
//         floor): rocprof shows VALUBusy 20%, hbm 43% peak, VGPR=36 -> huge
//         register headroom. This version doubles MLP to 16 row-loads in
//         flight per wave (8 edges/subgroup), cuts the index loads to 4x int4,
//         the scale loads to 2 per-lane coalesced loads (lane j owns edge
//         e0+j), and makes the output store a single coalesced 8-lane store.
// (Round 1 resubmit: previous bench died at container acquire, not in the
//  kernel — source unchanged.)

#define D_FEAT 128

__device__ __forceinline__ int dot4_i8(unsigned a, unsigned b, int c) {
#if __has_builtin(__builtin_amdgcn_sdot4)
    return __builtin_amdgcn_sdot4((int)a, (int)b, c, false);
#else
    int r = c;
#pragma unroll
    for (int i = 0; i < 4; ++i) {
        int ai = (int)(a << (24 - 8 * i)) >> 24;
        int bi = (int)(b << (24 - 8 * i)) >> 24;
        r += ai * bi;
    }
    return r;
#endif
}

__device__ __forceinline__ unsigned pack4(int b0, int b1, int b2, int b3) {
    return (unsigned)(b0 & 0xff) | ((unsigned)(b1 & 0xff) << 8) |
           ((unsigned)(b2 & 0xff) << 16) | ((unsigned)(b3 & 0xff) << 24);
}

__global__ __launch_bounds__(256) void quantize_rows(
    const float* __restrict__ h,
    signed char* __restrict__ q,
    float* __restrict__ scale,
    int n_rows)
{
    int tid  = blockIdx.x * blockDim.x + threadIdx.x;
    int row  = tid >> 4;
    int lane = tid & 15;
    if (row >= n_rows) return;

    const float4* p = (const float4*)(h + (long)row * D_FEAT) + lane * 2;
    float4 x = p[0];
    float4 y = p[1];

    float m = fabsf(x.x);
    m = fmaxf(m, fabsf(x.y)); m = fmaxf(m, fabsf(x.z)); m = fmaxf(m, fabsf(x.w));
    m = fmaxf(m, fabsf(y.x)); m = fmaxf(m, fabsf(y.y));
    m = fmaxf(m, fabsf(y.z)); m = fmaxf(m, fabsf(y.w));

    m = fmaxf(m, __shfl_xor(m, 8));
    m = fmaxf(m, __shfl_xor(m, 4));
    m = fmaxf(m, __shfl_xor(m, 2));
    m = fmaxf(m, __shfl_xor(m, 1));

    float inv = (m > 0.f) ? (127.f / m) : 0.f;

    int b0 = (int)rintf(x.x * inv), b1 = (int)rintf(x.y * inv);
    int b2 = (int)rintf(x.z * inv), b3 = (int)rintf(x.w * inv);
    int b4 = (int)rintf(y.x * inv), b5 = (int)rintf(y.y * inv);
    int b6 = (int)rintf(y.z * inv), b7 = (int)rintf(y.w * inv);

    uint2 o;
    o.x = pack4(b0, b1, b2, b3);
    o.y = pack4(b4, b5, b6, b7);
    ((uint2*)(q + (long)row * D_FEAT))[lane] = o;

    if (lane == 0) scale[row] = m * (1.f / 127.f);
}

// Unsorted gather, 8 edges per 8-lane subgroup (16 row loads in flight/wave).
__global__ __launch_bounds__(256) void edge_dot_i8_b8(
    const signed char* __restrict__ q,
    const float* __restrict__ scale,
    const int* __restrict__ src,
    const int* __restrict__ dst,
    float* __restrict__ out,
    int n_edges)
{
    int tid  = blockIdx.x * blockDim.x + threadIdx.x;
    int sub  = tid >> 3;          // subgroup id
    int lane = tid & 7;
    int e0   = sub * 8;
    if (e0 >= n_edges) return;

    // Per-lane owned edge (for scale + store); clamp for the tail.
    int me   = min(e0 + lane, n_edges - 1);
    int msrc = src[me];           // L1-hot re-read, coalesced, issued early
    int mdst = dst[me];

    // Subgroup-wide index vectors: 4 coalesced int4 loads (e0 is 8-aligned).
    int4 sa, sb, da, db;
    if (e0 + 8 <= n_edges) {
        const int4* sp = (const int4*)(src + e0);
        const int4* dp = (const int4*)(dst + e0);
        sa = sp[0]; sb = sp[1];
        da = dp[0]; db = dp[1];
    } else {
        int last = n_edges - 1;
        sa.x = src[e0];
        sa.y = src[min(e0 + 1, last)];
        sa.z = src[min(e0 + 2, last)];
        sa.w = src[min(e0 + 3, last)];
        sb.x = src[min(e0 + 4, last)];
        sb.y = src[min(e0 + 5, last)];
        sb.z = src[min(e0 + 6, last)];
        sb.w = src[min(e0 + 7, last)];
        da.x = dst[e0];
        da.y = dst[min(e0 + 1, last)];
        da.z = dst[min(e0 + 2, last)];
        da.w = dst[min(e0 + 3, last)];
        db.x = dst[min(e0 + 4, last)];
        db.y = dst[min(e0 + 5, last)];
        db.z = dst[min(e0 + 6, last)];
        db.w = dst[min(e0 + 7, last)];
    }

    // Issue all 16 row loads before any use: 16 outstanding misses/wave.
    const uint4* qb = (const uint4*)q;   // row = 8 uint4
    uint4 a0 = qb[(long)sa.x * 8 + lane];
    uint4 a1 = qb[(long)sa.y * 8 + lane];
    uint4 a2 = qb[(long)sa.z * 8 + lane];
    uint4 a3 = qb[(long)sa.w * 8 + lane];
    uint4 a4 = qb[(long)sb.x * 8 + lane];
    uint4 a5 = qb[(long)sb.y * 8 + lane];
    uint4 a6 = qb[(long)sb.z * 8 + lane];
    uint4 a7 = qb[(long)sb.w * 8 + lane];
    uint4 c0 = qb[(long)da.x * 8 + lane];
    uint4 c1 = qb[(long)da.y * 8 + lane];
    uint4 c2 = qb[(long)da.z * 8 + lane];
    uint4 c3 = qb[(long)da.w * 8 + lane];
    uint4 c4 = qb[(long)db.x * 8 + lane];
    uint4 c5 = qb[(long)db.y * 8 + lane];
    uint4 c6 = qb[(long)db.z * 8 + lane];
    uint4 c7 = qb[(long)db.w * 8 + lane];

    // Only 2 scale loads per lane (its own edge), overlapped with row loads.
    float fs = scale[msrc] * scale[mdst];

    int i0 = dot4_i8(a0.x, c0.x, 0);
    i0 = dot4_i8(a0.y, c0.y, i0);
    i0 = dot4_i8(a0.z, c0.z, i0);
    i0 = dot4_i8(a0.w, c0.w, i0);

    int i1 = dot4_i8(a1.x, c1.x, 0);
    i1 = dot4_i8(a1.y, c1.y, i1);
    i1 = dot4_i8(a1.z, c1.z, i1);
    i1 = dot4_i8(a1.w, c1.w, i1);

    int i2 = dot4_i8(a2.x, c2.x, 0);
    i2 = dot4_i8(a2.y, c2.y, i2);
    i2 = dot4_i8(a2.z, c2.z, i2);
    i2 = dot4_i8(a2.w, c2.w, i2);

    int i3 = dot4_i8(a3.x, c3.x, 0);
    i3 = dot4_i8(a3.y, c3.y, i3);
    i3 = dot4_i8(a3.z, c3.z, i3);
    i3 = dot4_i8(a3.w, c3.w, i3);

    int i4 = dot4_i8(a4.x, c4.x, 0);
    i4 = dot4_i8(a4.y, c4.y, i4);
    i4 = dot4_i8(a4.z, c4.z, i4);
    i4 = dot4_i8(a4.w, c4.w, i4);

    int i5 = dot4_i8(a5.x, c5.x, 0);
    i5 = dot4_i8(a5.y, c5.y, i5);
    i5 = dot4_i8(a5.z, c5.z, i5);
    i5 = dot4_i8(a5.w, c5.w, i5);

    int i6 = dot4_i8(a6.x, c6.x, 0);
    i6 = dot4_i8(a6.y, c6.y, i6);
    i6 = dot4_i8(a6.z, c6.z, i6);
    i6 = dot4_i8(a6.w, c6.w, i6);

    int i7 = dot4_i8(a7.x, c7.x, 0);
    i7 = dot4_i8(a7.y, c7.y, i7);
    i7 = dot4_i8(a7.z, c7.z, i7);
    i7 = dot4_i8(a7.w, c7.w, i7);

    i0 += __shfl_xor(i0, 4); i0 += __shfl_xor(i0, 2); i0 += __shfl_xor(i0, 1);
    i1 += __shfl_xor(i1, 4); i1 += __shfl_xor(i1, 2); i1 += __shfl_xor(i1, 1);
    i2 += __shfl_xor(i2, 4); i2 += __shfl_xor(i2, 2); i2 += __shfl_xor(i2, 1);
    i3 += __shfl_xor(i3, 4); i3 += __shfl_xor(i3, 2); i3 += __shfl_xor(i3, 1);
    i4 += __shfl_xor(i4, 4); i4 += __shfl_xor(i4, 2); i4 += __shfl_xor(i4, 1);
    i5 += __shfl_xor(i5, 4); i5 += __shfl_xor(i5, 2); i5 += __shfl_xor(i5, 1);
    i6 += __shfl_xor(i6, 4); i6 += __shfl_xor(i6, 2); i6 += __shfl_xor(i6, 1);
    i7 += __shfl_xor(i7, 4); i7 += __shfl_xor(i7, 2); i7 += __shfl_xor(i7, 1);

    // Select the owning lane's result (cndmask chain, no dynamic indexing)
    // and do ONE coalesced 8-lane store per subgroup.
    int mi = i0;
    if (lane == 1) mi = i1;
    if (lane == 2) mi = i2;
    if (lane == 3) mi = i3;
    if (lane == 4) mi = i4;
    if (lane == 5) mi = i5;
    if (lane == 6) mi = i6;
    if (lane == 7) mi = i7;

    if (e0 + lane < n_edges) out[e0 + lane] = (float)mi * fs;
}

// Last-resort f32 direct gather (workspace too small).
__global__ __launch_bounds__(256) void edge_dot_f32(
    const float* __restrict__ h,
    const int* __restrict__ src,
    const int* __restrict__ dst,
    float* __restrict__ out,
    int n_edges)
{
    int tid  = blockIdx.x * blockDim.x + threadIdx.x;
    int e    = tid >> 4;
    int lane = tid & 15;
    if (e >= n_edges) return;

    long srow = (long)src[e] * D_FEAT;
    long drow = (long)dst[e] * D_FEAT;

    const float4* hs = (const float4*)(h + srow) + lane * 2;
    const float4* hd = (const float4*)(h + drow) + lane * 2;
    float4 a0 = hs[0], a1 = hs[1], b0 = hd[0], b1 = hd[1];

    float acc = a0.x * b0.x + a0.y * b0.y + a0.z * b0.z + a0.w * b0.w
              + a1.x * b1.x + a1.y * b1.y + a1.z * b1.z + a1.w * b1.w;

    acc += __shfl_xor(acc, 8);
    acc += __shfl_xor(acc, 4);
    acc += __shfl_xor(acc, 2);
    acc += __shfl_xor(acc, 1);

    if (lane == 0) out[e] = acc;
}

extern "C" void kernel_launch(void* const* d_in, const int* in_sizes, int n_in,
                              void* d_out, int out_size, void* d_ws, size_t ws_size,
                              hipStream_t stream)
{
    const float* h   = (const float*)d_in[0];
    const int*   src = (const int*)d_in[1];
    const int*   dst = (const int*)d_in[2];
    float*       out = (float*)d_out;

    int n_edges = in_sizes[1];
    int n_feat  = in_sizes[0];
    int n_rows  = n_feat / D_FEAT;

    size_t q_sz   = (size_t)n_feat;
    size_t sc_off = (q_sz + 255) & ~(size_t)255;
    size_t need   = sc_off + (size_t)n_rows * sizeof(float);

    int block = 256;

    if (ws_size >= need) {
        signed char* q     = (signed char*)d_ws;
        float*       scale = (float*)((char*)d_ws + sc_off);

        int grid_quant = (n_rows * 16 + block - 1) / block;
        int n_sub      = (n_edges + 7) / 8;
        long threads   = (long)n_sub * 8;
        int grid_dot   = (int)((threads + block - 1) / block);

        quantize_rows<<<grid_quant, block, 0, stream>>>(h, q, scale, n_rows);
        edge_dot_i8_b8<<<grid_dot, block, 0, stream>>>(q, scale, src, dst, out, n_edges);
    } else {
        int grid_dot = (n_edges * 16 + block - 1) / block;
        edge_dot_f32<<<grid_dot, block, 0, stream>>>(h, src, dst, out, n_edges);
    }
}

// Round 3
// 139.138 us; speedup vs baseline: 1.0005x; 1.0005x over previous
//
#include <hip/hip_runtime.h>

// out[e] = dot(h[src[e]], h[dst[e]]), D=128, h f32.
// Pass 1: per-row int8 quantization (q = rint(x*127/rowmax), scale = rowmax/127).
// Pass 2: unsorted gather, 8 edges per 8-lane subgroup.
//
// Round 2 post-mortem: b8 batching did NOT change dur (48.9us) and VGPR
// stayed 36 -> the machine scheduler sank the 16 row loads into the
// consumption chain, reusing ~2 destination registers (MLP unchanged).
// Round 3: pin the schedule with __builtin_amdgcn_sched_barrier(0) after
// the load block. This forces all 16 loads to issue before any dot4,
// requiring ~64 live dest VGPRs (VGPR should jump to ~100+). Consumers
// after the barrier still wait incrementally on vmcnt, so edge-0 compute
// overlaps edges 1..7 in flight.

#define D_FEAT 128

__device__ __forceinline__ int dot4_i8(unsigned a, unsigned b, int c) {
#if __has_builtin(__builtin_amdgcn_sdot4)
    return __builtin_amdgcn_sdot4((int)a, (int)b, c, false);
#else
    int r = c;
#pragma unroll
    for (int i = 0; i < 4; ++i) {
        int ai = (int)(a << (24 - 8 * i)) >> 24;
        int bi = (int)(b << (24 - 8 * i)) >> 24;
        r += ai * bi;
    }
    return r;
#endif
}

__device__ __forceinline__ unsigned pack4(int b0, int b1, int b2, int b3) {
    return (unsigned)(b0 & 0xff) | ((unsigned)(b1 & 0xff) << 8) |
           ((unsigned)(b2 & 0xff) << 16) | ((unsigned)(b3 & 0xff) << 24);
}

__global__ __launch_bounds__(256) void quantize_rows(
    const float* __restrict__ h,
    signed char* __restrict__ q,
    float* __restrict__ scale,
    int n_rows)
{
    int tid  = blockIdx.x * blockDim.x + threadIdx.x;
    int row  = tid >> 4;
    int lane = tid & 15;
    if (row >= n_rows) return;

    const float4* p = (const float4*)(h + (long)row * D_FEAT) + lane * 2;
    float4 x = p[0];
    float4 y = p[1];

    float m = fabsf(x.x);
    m = fmaxf(m, fabsf(x.y)); m = fmaxf(m, fabsf(x.z)); m = fmaxf(m, fabsf(x.w));
    m = fmaxf(m, fabsf(y.x)); m = fmaxf(m, fabsf(y.y));
    m = fmaxf(m, fabsf(y.z)); m = fmaxf(m, fabsf(y.w));

    m = fmaxf(m, __shfl_xor(m, 8));
    m = fmaxf(m, __shfl_xor(m, 4));
    m = fmaxf(m, __shfl_xor(m, 2));
    m = fmaxf(m, __shfl_xor(m, 1));

    float inv = (m > 0.f) ? (127.f / m) : 0.f;

    int b0 = (int)rintf(x.x * inv), b1 = (int)rintf(x.y * inv);
    int b2 = (int)rintf(x.z * inv), b3 = (int)rintf(x.w * inv);
    int b4 = (int)rintf(y.x * inv), b5 = (int)rintf(y.y * inv);
    int b6 = (int)rintf(y.z * inv), b7 = (int)rintf(y.w * inv);

    uint2 o;
    o.x = pack4(b0, b1, b2, b3);
    o.y = pack4(b4, b5, b6, b7);
    ((uint2*)(q + (long)row * D_FEAT))[lane] = o;

    if (lane == 0) scale[row] = m * (1.f / 127.f);
}

// Unsorted gather, 8 edges per 8-lane subgroup, schedule pinned so all 16
// row loads are issued before any consumption (true 16-deep MLP per wave).
__global__ __launch_bounds__(256) void edge_dot_i8_b8(
    const signed char* __restrict__ q,
    const float* __restrict__ scale,
    const int* __restrict__ src,
    const int* __restrict__ dst,
    float* __restrict__ out,
    int n_edges)
{
    int tid  = blockIdx.x * blockDim.x + threadIdx.x;
    int sub  = tid >> 3;          // subgroup id
    int lane = tid & 7;
    int e0   = sub * 8;
    if (e0 >= n_edges) return;

    // Per-lane owned edge (for scale + store); clamp for the tail.
    int me   = min(e0 + lane, n_edges - 1);
    int msrc = src[me];           // L1-hot re-read, coalesced, issued early
    int mdst = dst[me];

    // Subgroup-wide index vectors: 4 coalesced int4 loads (e0 is 8-aligned).
    int4 sa, sb, da, db;
    if (e0 + 8 <= n_edges) {
        const int4* sp = (const int4*)(src + e0);
        const int4* dp = (const int4*)(dst + e0);
        sa = sp[0]; sb = sp[1];
        da = dp[0]; db = dp[1];
    } else {
        int last = n_edges - 1;
        sa.x = src[e0];
        sa.y = src[min(e0 + 1, last)];
        sa.z = src[min(e0 + 2, last)];
        sa.w = src[min(e0 + 3, last)];
        sb.x = src[min(e0 + 4, last)];
        sb.y = src[min(e0 + 5, last)];
        sb.z = src[min(e0 + 6, last)];
        sb.w = src[min(e0 + 7, last)];
        da.x = dst[e0];
        da.y = dst[min(e0 + 1, last)];
        da.z = dst[min(e0 + 2, last)];
        da.w = dst[min(e0 + 3, last)];
        db.x = dst[min(e0 + 4, last)];
        db.y = dst[min(e0 + 5, last)];
        db.z = dst[min(e0 + 6, last)];
        db.w = dst[min(e0 + 7, last)];
    }

    // Issue all 16 row loads + 2 scale loads before ANY use.
    const uint4* qb = (const uint4*)q;   // row = 8 uint4
    uint4 a0 = qb[(long)sa.x * 8 + lane];
    uint4 a1 = qb[(long)sa.y * 8 + lane];
    uint4 a2 = qb[(long)sa.z * 8 + lane];
    uint4 a3 = qb[(long)sa.w * 8 + lane];
    uint4 a4 = qb[(long)sb.x * 8 + lane];
    uint4 a5 = qb[(long)sb.y * 8 + lane];
    uint4 a6 = qb[(long)sb.z * 8 + lane];
    uint4 a7 = qb[(long)sb.w * 8 + lane];
    uint4 c0 = qb[(long)da.x * 8 + lane];
    uint4 c1 = qb[(long)da.y * 8 + lane];
    uint4 c2 = qb[(long)da.z * 8 + lane];
    uint4 c3 = qb[(long)da.w * 8 + lane];
    uint4 c4 = qb[(long)db.x * 8 + lane];
    uint4 c5 = qb[(long)db.y * 8 + lane];
    uint4 c6 = qb[(long)db.z * 8 + lane];
    uint4 c7 = qb[(long)db.w * 8 + lane];

    float ssrc = scale[msrc];
    float sdst = scale[mdst];

    // Pin: nothing may cross this point in either direction. Forces the
    // machine scheduler to keep all 16 loads outstanding (Round 2 showed
    // it otherwise serializes them down to ~2 live destinations, VGPR=36).
    __builtin_amdgcn_sched_barrier(0);

    float fs = ssrc * sdst;

    int i0 = dot4_i8(a0.x, c0.x, 0);
    i0 = dot4_i8(a0.y, c0.y, i0);
    i0 = dot4_i8(a0.z, c0.z, i0);
    i0 = dot4_i8(a0.w, c0.w, i0);

    int i1 = dot4_i8(a1.x, c1.x, 0);
    i1 = dot4_i8(a1.y, c1.y, i1);
    i1 = dot4_i8(a1.z, c1.z, i1);
    i1 = dot4_i8(a1.w, c1.w, i1);

    int i2 = dot4_i8(a2.x, c2.x, 0);
    i2 = dot4_i8(a2.y, c2.y, i2);
    i2 = dot4_i8(a2.z, c2.z, i2);
    i2 = dot4_i8(a2.w, c2.w, i2);

    int i3 = dot4_i8(a3.x, c3.x, 0);
    i3 = dot4_i8(a3.y, c3.y, i3);
    i3 = dot4_i8(a3.z, c3.z, i3);
    i3 = dot4_i8(a3.w, c3.w, i3);

    int i4 = dot4_i8(a4.x, c4.x, 0);
    i4 = dot4_i8(a4.y, c4.y, i4);
    i4 = dot4_i8(a4.z, c4.z, i4);
    i4 = dot4_i8(a4.w, c4.w, i4);

    int i5 = dot4_i8(a5.x, c5.x, 0);
    i5 = dot4_i8(a5.y, c5.y, i5);
    i5 = dot4_i8(a5.z, c5.z, i5);
    i5 = dot4_i8(a5.w, c5.w, i5);

    int i6 = dot4_i8(a6.x, c6.x, 0);
    i6 = dot4_i8(a6.y, c6.y, i6);
    i6 = dot4_i8(a6.z, c6.z, i6);
    i6 = dot4_i8(a6.w, c6.w, i6);

    int i7 = dot4_i8(a7.x, c7.x, 0);
    i7 = dot4_i8(a7.y, c7.y, i7);
    i7 = dot4_i8(a7.z, c7.z, i7);
    i7 = dot4_i8(a7.w, c7.w, i7);

    i0 += __shfl_xor(i0, 4); i0 += __shfl_xor(i0, 2); i0 += __shfl_xor(i0, 1);
    i1 += __shfl_xor(i1, 4); i1 += __shfl_xor(i1, 2); i1 += __shfl_xor(i1, 1);
    i2 += __shfl_xor(i2, 4); i2 += __shfl_xor(i2, 2); i2 += __shfl_xor(i2, 1);
    i3 += __shfl_xor(i3, 4); i3 += __shfl_xor(i3, 2); i3 += __shfl_xor(i3, 1);
    i4 += __shfl_xor(i4, 4); i4 += __shfl_xor(i4, 2); i4 += __shfl_xor(i4, 1);
    i5 += __shfl_xor(i5, 4); i5 += __shfl_xor(i5, 2); i5 += __shfl_xor(i5, 1);
    i6 += __shfl_xor(i6, 4); i6 += __shfl_xor(i6, 2); i6 += __shfl_xor(i6, 1);
    i7 += __shfl_xor(i7, 4); i7 += __shfl_xor(i7, 2); i7 += __shfl_xor(i7, 1);

    // Select the owning lane's result (cndmask chain, no dynamic indexing)
    // and do ONE coalesced 8-lane store per subgroup.
    int mi = i0;
    if (lane == 1) mi = i1;
    if (lane == 2) mi = i2;
    if (lane == 3) mi = i3;
    if (lane == 4) mi = i4;
    if (lane == 5) mi = i5;
    if (lane == 6) mi = i6;
    if (lane == 7) mi = i7;

    if (e0 + lane < n_edges) out[e0 + lane] = (float)mi * fs;
}

// Last-resort f32 direct gather (workspace too small).
__global__ __launch_bounds__(256) void edge_dot_f32(
    const float* __restrict__ h,
    const int* __restrict__ src,
    const int* __restrict__ dst,
    float* __restrict__ out,
    int n_edges)
{
    int tid  = blockIdx.x * blockDim.x + threadIdx.x;
    int e    = tid >> 4;
    int lane = tid & 15;
    if (e >= n_edges) return;

    long srow = (long)src[e] * D_FEAT;
    long drow = (long)dst[e] * D_FEAT;

    const float4* hs = (const float4*)(h + srow) + lane * 2;
    const float4* hd = (const float4*)(h + drow) + lane * 2;
    float4 a0 = hs[0], a1 = hs[1], b0 = hd[0], b1 = hd[1];

    float acc = a0.x * b0.x + a0.y * b0.y + a0.z * b0.z + a0.w * b0.w
              + a1.x * b1.x + a1.y * b1.y + a1.z * b1.z + a1.w * b1.w;

    acc += __shfl_xor(acc, 8);
    acc += __shfl_xor(acc, 4);
    acc += __shfl_xor(acc, 2);
    acc += __shfl_xor(acc, 1);

    if (lane == 0) out[e] = acc;
}

extern "C" void kernel_launch(void* const* d_in, const int* in_sizes, int n_in,
                              void* d_out, int out_size, void* d_ws, size_t ws_size,
                              hipStream_t stream)
{
    const float* h   = (const float*)d_in[0];
    const int*   src = (const int*)d_in[1];
    const int*   dst = (const int*)d_in[2];
    float*       out = (float*)d_out;

    int n_edges = in_sizes[1];
    int n_feat  = in_sizes[0];
    int n_rows  = n_feat / D_FEAT;

    size_t q_sz   = (size_t)n_feat;
    size_t sc_off = (q_sz + 255) & ~(size_t)255;
    size_t need   = sc_off + (size_t)n_rows * sizeof(float);

    int block = 256;

    if (ws_size >= need) {
        signed char* q     = (signed char*)d_ws;
        float*       scale = (float*)((char*)d_ws + sc_off);

        int grid_quant = (n_rows * 16 + block - 1) / block;
        int n_sub      = (n_edges + 7) / 8;
        long threads   = (long)n_sub * 8;
        int grid_dot   = (int)((threads + block - 1) / block);

        quantize_rows<<<grid_quant, block, 0, stream>>>(h, q, scale, n_rows);
        edge_dot_i8_b8<<<grid_dot, block, 0, stream>>>(q, scale, src, dst, out, n_edges);
    } else {
        int grid_dot = (n_edges * 16 + block - 1) / block;
        edge_dot_f32<<<grid_dot, block, 0, stream>>>(h, src, dst, out, n_edges);
    }
}

// Round 4
// 138.475 us; speedup vs baseline: 1.0053x; 1.0048x over previous
//
#include <hip/hip_runtime.h>

// out[e] = dot(h[src[e]], h[dst[e]]), D=128, h f32.
// Pass 1: per-row int8 quantization (q = rint(x*127/rowmax), scale = rowmax/127).
// Pass 2: unsorted gather, 8 edges per 8-lane subgroup.
//
// Round 2/3 post-mortem: source-level batching AND sched_barrier(0) both
// failed to raise MLP -- VGPR stayed 36/44 (16 live uint4 dests need 64),
// proving the compiler serializes the loads into ~2-3 live destinations.
// Round 4: inline-asm global_load_dwordx4 (HK/AITER pattern). asm volatile
// loads are order-pinned and their dests MUST stay live until consumed.
// All VMEM in the region is asm (16 row loads + 2 scale loads), so vmcnt
// counting is exact: vmcnt(10) -> edges 0-3 ready; vmcnt(0) -> all.
// Each waitcnt is followed by sched_barrier(0) (rule: hipcc hoists
// register-only consumers past inline-asm waitcnt otherwise).

#define D_FEAT 128

typedef unsigned int u32x4 __attribute__((ext_vector_type(4)));

__device__ __forceinline__ int dot4_i8(unsigned a, unsigned b, int c) {
#if __has_builtin(__builtin_amdgcn_sdot4)
    return __builtin_amdgcn_sdot4((int)a, (int)b, c, false);
#else
    int r = c;
#pragma unroll
    for (int i = 0; i < 4; ++i) {
        int ai = (int)(a << (24 - 8 * i)) >> 24;
        int bi = (int)(b << (24 - 8 * i)) >> 24;
        r += ai * bi;
    }
    return r;
#endif
}

__device__ __forceinline__ unsigned pack4(int b0, int b1, int b2, int b3) {
    return (unsigned)(b0 & 0xff) | ((unsigned)(b1 & 0xff) << 8) |
           ((unsigned)(b2 & 0xff) << 16) | ((unsigned)(b3 & 0xff) << 24);
}

__global__ __launch_bounds__(256) void quantize_rows(
    const float* __restrict__ h,
    signed char* __restrict__ q,
    float* __restrict__ scale,
    int n_rows)
{
    int tid  = blockIdx.x * blockDim.x + threadIdx.x;
    int row  = tid >> 4;
    int lane = tid & 15;
    if (row >= n_rows) return;

    const float4* p = (const float4*)(h + (long)row * D_FEAT) + lane * 2;
    float4 x = p[0];
    float4 y = p[1];

    float m = fabsf(x.x);
    m = fmaxf(m, fabsf(x.y)); m = fmaxf(m, fabsf(x.z)); m = fmaxf(m, fabsf(x.w));
    m = fmaxf(m, fabsf(y.x)); m = fmaxf(m, fabsf(y.y));
    m = fmaxf(m, fabsf(y.z)); m = fmaxf(m, fabsf(y.w));

    m = fmaxf(m, __shfl_xor(m, 8));
    m = fmaxf(m, __shfl_xor(m, 4));
    m = fmaxf(m, __shfl_xor(m, 2));
    m = fmaxf(m, __shfl_xor(m, 1));

    float inv = (m > 0.f) ? (127.f / m) : 0.f;

    int b0 = (int)rintf(x.x * inv), b1 = (int)rintf(x.y * inv);
    int b2 = (int)rintf(x.z * inv), b3 = (int)rintf(x.w * inv);
    int b4 = (int)rintf(y.x * inv), b5 = (int)rintf(y.y * inv);
    int b6 = (int)rintf(y.z * inv), b7 = (int)rintf(y.w * inv);

    uint2 o;
    o.x = pack4(b0, b1, b2, b3);
    o.y = pack4(b4, b5, b6, b7);
    ((uint2*)(q + (long)row * D_FEAT))[lane] = o;

    if (lane == 0) scale[row] = m * (1.f / 127.f);
}

// Unsorted gather, 8 edges per 8-lane subgroup; 16 row loads pinned in
// flight via inline asm (true MLP this time -- verify via VGPR >= 100).
__global__ __launch_bounds__(256) void edge_dot_i8_b8(
    const signed char* __restrict__ q,
    const float* __restrict__ scale,
    const int* __restrict__ src,
    const int* __restrict__ dst,
    float* __restrict__ out,
    int n_edges)
{
    int tid  = blockIdx.x * blockDim.x + threadIdx.x;
    int sub  = tid >> 3;          // subgroup id
    int lane = tid & 7;
    int e0   = sub * 8;
    if (e0 >= n_edges) return;

    // Per-lane owned edge (for scale + store); clamp for the tail.
    int me   = min(e0 + lane, n_edges - 1);
    int msrc = src[me];
    int mdst = dst[me];

    // Subgroup-wide index vectors: 4 coalesced int4 loads (e0 is 8-aligned).
    int4 sa, sb, da, db;
    if (e0 + 8 <= n_edges) {
        const int4* sp = (const int4*)(src + e0);
        const int4* dp = (const int4*)(dst + e0);
        sa = sp[0]; sb = sp[1];
        da = dp[0]; db = dp[1];
    } else {
        int last = n_edges - 1;
        sa.x = src[e0];
        sa.y = src[min(e0 + 1, last)];
        sa.z = src[min(e0 + 2, last)];
        sa.w = src[min(e0 + 3, last)];
        sb.x = src[min(e0 + 4, last)];
        sb.y = src[min(e0 + 5, last)];
        sb.z = src[min(e0 + 6, last)];
        sb.w = src[min(e0 + 7, last)];
        da.x = dst[e0];
        da.y = dst[min(e0 + 1, last)];
        da.z = dst[min(e0 + 2, last)];
        da.w = dst[min(e0 + 3, last)];
        db.x = dst[min(e0 + 4, last)];
        db.y = dst[min(e0 + 5, last)];
        db.z = dst[min(e0 + 6, last)];
        db.w = dst[min(e0 + 7, last)];
    }

    long loff = (long)(lane << 4);

    const signed char* pa0 = q + (((long)sa.x) << 7) + loff;
    const signed char* pc0 = q + (((long)da.x) << 7) + loff;
    const signed char* pa1 = q + (((long)sa.y) << 7) + loff;
    const signed char* pc1 = q + (((long)da.y) << 7) + loff;
    const signed char* pa2 = q + (((long)sa.z) << 7) + loff;
    const signed char* pc2 = q + (((long)da.z) << 7) + loff;
    const signed char* pa3 = q + (((long)sa.w) << 7) + loff;
    const signed char* pc3 = q + (((long)da.w) << 7) + loff;
    const signed char* pa4 = q + (((long)sb.x) << 7) + loff;
    const signed char* pc4 = q + (((long)db.x) << 7) + loff;
    const signed char* pa5 = q + (((long)sb.y) << 7) + loff;
    const signed char* pc5 = q + (((long)db.y) << 7) + loff;
    const signed char* pa6 = q + (((long)sb.z) << 7) + loff;
    const signed char* pc6 = q + (((long)db.z) << 7) + loff;
    const signed char* pa7 = q + (((long)sb.w) << 7) + loff;
    const signed char* pc7 = q + (((long)db.w) << 7) + loff;
    const float* pss = scale + msrc;
    const float* psd = scale + mdst;

    // Issue ALL VMEM as pinned asm: FIFO = a0,c0,a1,c1,...,a7,c7,ss,sd (18).
    u32x4 a0, a1, a2, a3, a4, a5, a6, a7;
    u32x4 c0, c1, c2, c3, c4, c5, c6, c7;
    float ssrc, sdst;
    asm volatile("global_load_dwordx4 %0, %1, off" : "=v"(a0) : "v"(pa0) : "memory");
    asm volatile("global_load_dwordx4 %0, %1, off" : "=v"(c0) : "v"(pc0) : "memory");
    asm volatile("global_load_dwordx4 %0, %1, off" : "=v"(a1) : "v"(pa1) : "memory");
    asm volatile("global_load_dwordx4 %0, %1, off" : "=v"(c1) : "v"(pc1) : "memory");
    asm volatile("global_load_dwordx4 %0, %1, off" : "=v"(a2) : "v"(pa2) : "memory");
    asm volatile("global_load_dwordx4 %0, %1, off" : "=v"(c2) : "v"(pc2) : "memory");
    asm volatile("global_load_dwordx4 %0, %1, off" : "=v"(a3) : "v"(pa3) : "memory");
    asm volatile("global_load_dwordx4 %0, %1, off" : "=v"(c3) : "v"(pc3) : "memory");
    asm volatile("global_load_dwordx4 %0, %1, off" : "=v"(a4) : "v"(pa4) : "memory");
    asm volatile("global_load_dwordx4 %0, %1, off" : "=v"(c4) : "v"(pc4) : "memory");
    asm volatile("global_load_dwordx4 %0, %1, off" : "=v"(a5) : "v"(pa5) : "memory");
    asm volatile("global_load_dwordx4 %0, %1, off" : "=v"(c5) : "v"(pc5) : "memory");
    asm volatile("global_load_dwordx4 %0, %1, off" : "=v"(a6) : "v"(pa6) : "memory");
    asm volatile("global_load_dwordx4 %0, %1, off" : "=v"(c6) : "v"(pc6) : "memory");
    asm volatile("global_load_dwordx4 %0, %1, off" : "=v"(a7) : "v"(pa7) : "memory");
    asm volatile("global_load_dwordx4 %0, %1, off" : "=v"(c7) : "v"(pc7) : "memory");
    asm volatile("global_load_dword %0, %1, off" : "=v"(ssrc) : "v"(pss) : "memory");
    asm volatile("global_load_dword %0, %1, off" : "=v"(sdst) : "v"(psd) : "memory");

    // First 8 loads (edges 0-3) done when <=10 outstanding.
    asm volatile("s_waitcnt vmcnt(10)" ::: "memory");
    __builtin_amdgcn_sched_barrier(0);

    int i0 = dot4_i8(a0[0], c0[0], 0);
    i0 = dot4_i8(a0[1], c0[1], i0);
    i0 = dot4_i8(a0[2], c0[2], i0);
    i0 = dot4_i8(a0[3], c0[3], i0);

    int i1 = dot4_i8(a1[0], c1[0], 0);
    i1 = dot4_i8(a1[1], c1[1], i1);
    i1 = dot4_i8(a1[2], c1[2], i1);
    i1 = dot4_i8(a1[3], c1[3], i1);

    int i2 = dot4_i8(a2[0], c2[0], 0);
    i2 = dot4_i8(a2[1], c2[1], i2);
    i2 = dot4_i8(a2[2], c2[2], i2);
    i2 = dot4_i8(a2[3], c2[3], i2);

    int i3 = dot4_i8(a3[0], c3[0], 0);
    i3 = dot4_i8(a3[1], c3[1], i3);
    i3 = dot4_i8(a3[2], c3[2], i3);
    i3 = dot4_i8(a3[3], c3[3], i3);

    i0 += __shfl_xor(i0, 4); i0 += __shfl_xor(i0, 2); i0 += __shfl_xor(i0, 1);
    i1 += __shfl_xor(i1, 4); i1 += __shfl_xor(i1, 2); i1 += __shfl_xor(i1, 1);
    i2 += __shfl_xor(i2, 4); i2 += __shfl_xor(i2, 2); i2 += __shfl_xor(i2, 1);
    i3 += __shfl_xor(i3, 4); i3 += __shfl_xor(i3, 2); i3 += __shfl_xor(i3, 1);

    // Remaining loads (edges 4-7 + scales).
    asm volatile("s_waitcnt vmcnt(0)" ::: "memory");
    __builtin_amdgcn_sched_barrier(0);

    int i4 = dot4_i8(a4[0], c4[0], 0);
    i4 = dot4_i8(a4[1], c4[1], i4);
    i4 = dot4_i8(a4[2], c4[2], i4);
    i4 = dot4_i8(a4[3], c4[3], i4);

    int i5 = dot4_i8(a5[0], c5[0], 0);
    i5 = dot4_i8(a5[1], c5[1], i5);
    i5 = dot4_i8(a5[2], c5[2], i5);
    i5 = dot4_i8(a5[3], c5[3], i5);

    int i6 = dot4_i8(a6[0], c6[0], 0);
    i6 = dot4_i8(a6[1], c6[1], i6);
    i6 = dot4_i8(a6[2], c6[2], i6);
    i6 = dot4_i8(a6[3], c6[3], i6);

    int i7 = dot4_i8(a7[0], c7[0], 0);
    i7 = dot4_i8(a7[1], c7[1], i7);
    i7 = dot4_i8(a7[2], c7[2], i7);
    i7 = dot4_i8(a7[3], c7[3], i7);

    i4 += __shfl_xor(i4, 4); i4 += __shfl_xor(i4, 2); i4 += __shfl_xor(i4, 1);
    i5 += __shfl_xor(i5, 4); i5 += __shfl_xor(i5, 2); i5 += __shfl_xor(i5, 1);
    i6 += __shfl_xor(i6, 4); i6 += __shfl_xor(i6, 2); i6 += __shfl_xor(i6, 1);
    i7 += __shfl_xor(i7, 4); i7 += __shfl_xor(i7, 2); i7 += __shfl_xor(i7, 1);

    // Select the owning lane's result; one coalesced 8-lane store.
    int mi = i0;
    if (lane == 1) mi = i1;
    if (lane == 2) mi = i2;
    if (lane == 3) mi = i3;
    if (lane == 4) mi = i4;
    if (lane == 5) mi = i5;
    if (lane == 6) mi = i6;
    if (lane == 7) mi = i7;

    float fs = ssrc * sdst;
    if (e0 + lane < n_edges) out[e0 + lane] = (float)mi * fs;
}

// Last-resort f32 direct gather (workspace too small).
__global__ __launch_bounds__(256) void edge_dot_f32(
    const float* __restrict__ h,
    const int* __restrict__ src,
    const int* __restrict__ dst,
    float* __restrict__ out,
    int n_edges)
{
    int tid  = blockIdx.x * blockDim.x + threadIdx.x;
    int e    = tid >> 4;
    int lane = tid & 15;
    if (e >= n_edges) return;

    long srow = (long)src[e] * D_FEAT;
    long drow = (long)dst[e] * D_FEAT;

    const float4* hs = (const float4*)(h + srow) + lane * 2;
    const float4* hd = (const float4*)(h + drow) + lane * 2;
    float4 a0 = hs[0], a1 = hs[1], b0 = hd[0], b1 = hd[1];

    float acc = a0.x * b0.x + a0.y * b0.y + a0.z * b0.z + a0.w * b0.w
              + a1.x * b1.x + a1.y * b1.y + a1.z * b1.z + a1.w * b1.w;

    acc += __shfl_xor(acc, 8);
    acc += __shfl_xor(acc, 4);
    acc += __shfl_xor(acc, 2);
    acc += __shfl_xor(acc, 1);

    if (lane == 0) out[e] = acc;
}

extern "C" void kernel_launch(void* const* d_in, const int* in_sizes, int n_in,
                              void* d_out, int out_size, void* d_ws, size_t ws_size,
                              hipStream_t stream)
{
    const float* h   = (const float*)d_in[0];
    const int*   src = (const int*)d_in[1];
    const int*   dst = (const int*)d_in[2];
    float*       out = (float*)d_out;

    int n_edges = in_sizes[1];
    int n_feat  = in_sizes[0];
    int n_rows  = n_feat / D_FEAT;

    size_t q_sz   = (size_t)n_feat;
    size_t sc_off = (q_sz + 255) & ~(size_t)255;
    size_t need   = sc_off + (size_t)n_rows * sizeof(float);

    int block = 256;

    if (ws_size >= need) {
        signed char* q     = (signed char*)d_ws;
        float*       scale = (float*)((char*)d_ws + sc_off);

        int grid_quant = (n_rows * 16 + block - 1) / block;
        int n_sub      = (n_edges + 7) / 8;
        long threads   = (long)n_sub * 8;
        int grid_dot   = (int)((threads + block - 1) / block);

        quantize_rows<<<grid_quant, block, 0, stream>>>(h, q, scale, n_rows);
        edge_dot_i8_b8<<<grid_dot, block, 0, stream>>>(q, scale, src, dst, out, n_edges);
    } else {
        int grid_dot = (n_edges * 16 + block - 1) / block;
        edge_dot_f32<<<grid_dot, block, 0, stream>>>(h, src, dst, out, n_edges);
    }
}